// Round 3
// baseline (234.555 us; speedup 1.0000x reference)
//
#include <hip/hip_runtime.h>
#include <hip/hip_bf16.h>
#include <hip/hip_fp16.h>

#define B_  16
#define G_  4
#define CG  64
#define H_  64
#define W_  64
#define KK  9
#define HW  (H_ * W_)
#define IP  72            // padded i-stride (shorts) for sT rows: 144 B
#define PD  68            // padded spatial dim (64 + 2 each side)
#define XSLICE (PD * PD * CG)   // shorts per (b,g) slice of xTpad

typedef short    short8  __attribute__((ext_vector_type(8)));
typedef _Float16 half8   __attribute__((ext_vector_type(8)));
typedef _Float16 h2      __attribute__((ext_vector_type(2)));
typedef float    f32x4   __attribute__((ext_vector_type(4)));
typedef float    f32x16  __attribute__((ext_vector_type(16)));

__device__ __forceinline__ short f2h(float v) {
    _Float16 h = (_Float16)v;
    short s;
    __builtin_memcpy(&s, &h, 2);
    return s;
}

__device__ __forceinline__ unsigned int pk2h(float a, float b) {
    h2 h = { (_Float16)a, (_Float16)b };
    unsigned int u;
    __builtin_memcpy(&u, &h, 4);
    return u;
}

// bilinear combine of 2 packed fp16 channels via native v_pk_fma_f16
__device__ __forceinline__ unsigned int interp2h(unsigned int c00, unsigned int c01,
                                                 unsigned int c10, unsigned int c11,
                                                 h2 w00, h2 w01, h2 w10, h2 w11) {
    h2 v00, v01, v10, v11;
    __builtin_memcpy(&v00, &c00, 4);
    __builtin_memcpy(&v01, &c01, 4);
    __builtin_memcpy(&v10, &c10, 4);
    __builtin_memcpy(&v11, &c11, 4);
    h2 r = v00 * w00 + v01 * w01 + v10 * w10 + v11 * w11;
    unsigned int o;
    __builtin_memcpy(&o, &r, 4);
    return o;
}

// ---------------------------------------------------------------------------
// Merged prep kernel (fp16 staging).
//  blocks [0, 1024): interior x transpose. Block = (bg, 4-row y-tile).
//  blocks [1024, 1088): y-border zero rows (yp in {0,1,66,67}) per bg.
//  blocks [1088, +864): weight prep
//   dwA16[g][k][ot][kh][l][e] f16 = def_w[g][ot*16+(l&15)][kh*32+(l>>4)*8+e][k]
//     (A-fragment layout for mfma_f32_16x16x32: row=l&15, k=(l>>4)*8+e)
//   owA  [g][s][tm][q][jj][e]  f16 = off_w[g][j=tm*16+jj][(s&1)*32+q*8+e][s>>1]
// ---------------------------------------------------------------------------
__global__ __launch_bounds__(256)
void prep_all(const float* __restrict__ x,
              const float* __restrict__ off_w,
              const float* __restrict__ def_w,
              short* __restrict__ xTpad,
              short* __restrict__ dwA16,
              short* __restrict__ owA)
{
    const int blk = blockIdx.x;
    const int t   = threadIdx.x;

    if (blk < 1024) {
        const int bg = blk >> 4;
        const int y0 = (blk & 15) * 4;

        __shared__ unsigned int sBw[4 * CG * 33];   // 33792 B, f16x2 packed, padded

        const float* src = x + (size_t)bg * CG * HW + (size_t)y0 * W_;
        const int i  = t >> 2;          // channel 0..63
        const int x0 = (t & 3) * 16;    // col base 0/16/32/48

        // ---- load phase: 16 independent float4 loads per thread ----
        float4 v[4][4];
#pragma unroll
        for (int r = 0; r < 4; r++) {
            const float* sp = src + (size_t)i * HW + r * W_ + x0;
#pragma unroll
            for (int c = 0; c < 4; c++) v[r][c] = ((const float4*)sp)[c];
        }

        // ---- convert + stage (packed f16x2, padded row stride 33 words) ----
#pragma unroll
        for (int r = 0; r < 4; r++) {
#pragma unroll
            for (int c = 0; c < 4; c++) {
                const unsigned int u0 = pk2h(v[r][c].x, v[r][c].y);
                const unsigned int u1 = pk2h(v[r][c].z, v[r][c].w);
                const int base = (r * CG + i) * 33 + ((x0 + 4 * c) >> 1);
                sBw[base]     = u0;
                sBw[base + 1] = u1;
            }
        }
        __syncthreads();

        // ---- transpose-out phase: 16B stores, column reads hit 8 banks ----
        const short* sBs = (const short*)sBw;
        short* dst = xTpad + (size_t)bg * XSLICE;
#pragma unroll
        for (int r = 0; r < 4; r++) {
            const int yp = y0 + 2 + r;
            for (int task = t; task < PD * 8; task += 256) {
                const int ich = task & 7;
                const int xp  = task >> 3;
                const int xx  = xp - 2;
                short8 o = {0, 0, 0, 0, 0, 0, 0, 0};
                if ((unsigned)xx < (unsigned)W_) {
#pragma unroll
                    for (int e = 0; e < 8; e++)
                        o[e] = sBs[(r * CG + ich * 8 + e) * 66 + xx];
                }
                *(short8*)(dst + ((size_t)yp * PD + xp) * CG + ich * 8) = o;
            }
        }
        return;
    }

    if (blk < 1088) {
        // y-border zero rows: yp in {0,1} and {66,67}
        const int bg = blk - 1024;
        short* dstb = xTpad + (size_t)bg * XSLICE;
        const int4 z = {0, 0, 0, 0};
        int4* d0 = (int4*)(dstb);
        int4* d1 = (int4*)(dstb + (size_t)66 * PD * CG);
        const int n16 = (2 * PD * CG * 2) / 16;   // 1088 int4 per 2-row band
        for (int c = t; c < n16; c += 256) { d0[c] = z; d1[c] = z; }
        return;
    }

    // ---- weights part ----
    const int tid = (blk - 1088) * 256 + t;
    const int ndw = G_ * KK * 4096;               // 147456
    const int now = G_ * 18 * 2 * 4 * 16 * 8;     // 73728
    if (tid < ndw) {
        // dwA16[g][k][ot][kh][l][e]
        const int e  = tid & 7;
        const int l  = (tid >> 3) & 63;
        const int kh = (tid >> 9) & 1;
        const int ot = (tid >> 10) & 3;
        const int gk = tid >> 12;
        const int k  = gk % KK;
        const int g  = gk / KK;
        const int o  = ot * 16 + (l & 15);
        const int i  = kh * 32 + (l >> 4) * 8 + e;
        dwA16[tid] = f2h(def_w[((g * CG + o) * CG + i) * KK + k]);
    } else if (tid < ndw + now) {
        const int t2 = tid - ndw;
        const int e  = t2 & 7;
        const int jj = (t2 >> 3) & 15;
        const int q  = (t2 >> 7) & 3;
        const int tm = (t2 >> 9) & 1;
        const int gs = t2 >> 10;
        const int s  = gs % 18;
        const int g  = gs / 18;
        const int j  = tm * 16 + jj;
        const int rc = s >> 1;
        const int i  = (s & 1) * 32 + q * 8 + e;
        owA[t2] = (j < 18) ? f2h(off_w[((g * 18 + j) * CG + i) * KK + rc]) : (short)0;
    }
}

// ---------------------------------------------------------------------------
// Main fused kernel (fp16, BARRIER-FREE). Block = (b, g, h), 256 thr, 4 waves.
//  Each wave owns 16 output positions: gathers them (all 64 ch) and einsums
//  them via MFMA 16x16x32 (n=16 = the wave's own positions) -> sT buffers are
//  wave-private -> zero __syncthreads; waves drift independently and overlap
//  each other's memory stalls. T14 split: issue loads(k+1) -> einsum(k) ->
//  interp+write(k+1).
// ---------------------------------------------------------------------------
__global__ __launch_bounds__(256, 5)
void deform_main(const short* __restrict__ xTpad,
                 const float* __restrict__ off_b,
                 const float* __restrict__ def_b,
                 const short* __restrict__ dwA16,
                 const short* __restrict__ owA,
                 float* __restrict__ out)
{
    const int raw = blockIdx.x;
    const int r8  = raw & 7;
    const int h   = (raw >> 3) & 63;
    const int q8  = raw >> 9;
    const int bg  = q8 * 8 + r8;
    const int b   = bg >> 2;
    const int g   = bg & 3;

    __shared__ float2 pcs[KK][64];          // wave-private columns
    __shared__ short  sT[4][2][16 * IP];    // [wave][buf][pos][ch], wave-private

    const int t    = threadIdx.x;
    const int lane = t & 63;
    const int p    = t >> 6;          // wave id 0..3
    const int nn   = lane & 15;
    const int q    = lane >> 4;

    const short* xb = xTpad + (size_t)bg * XSLICE;

    // ---------------- Phase A: offset conv (MFMA 16x16x32 f16) ----------------
    {
        const short* owAg = owA + g * 18 * 1024;
        f32x4 oa0 = {0.f, 0.f, 0.f, 0.f};
        f32x4 oa1 = {0.f, 0.f, 0.f, 0.f};
#pragma unroll
        for (int rc = 0; rc < 9; rc++) {
            const int rr = rc / 3;
            const int cc = rc % 3;
            const short* cp = xb + ((h + rr + 1) * PD + (p * 16 + nn + cc + 1)) * CG + q * 8;
            const half8 b0 = *(const half8*)cp;          // s = 2rc   (ih=0)
            const half8 b1 = *(const half8*)(cp + 32);   // s = 2rc+1 (ih=32)
            const int s0 = rc * 2, s1 = rc * 2 + 1;
            const half8 a00 = *(const half8*)(owAg + ((s0 * 2 + 0) * 4 + q) * 128 + nn * 8);
            const half8 a01 = *(const half8*)(owAg + ((s0 * 2 + 1) * 4 + q) * 128 + nn * 8);
            const half8 a10 = *(const half8*)(owAg + ((s1 * 2 + 0) * 4 + q) * 128 + nn * 8);
            const half8 a11 = *(const half8*)(owAg + ((s1 * 2 + 1) * 4 + q) * 128 + nn * 8);
            oa0 = __builtin_amdgcn_mfma_f32_16x16x32_f16(a00, b0, oa0, 0, 0, 0);
            oa1 = __builtin_amdgcn_mfma_f32_16x16x32_f16(a01, b0, oa1, 0, 0, 0);
            oa0 = __builtin_amdgcn_mfma_f32_16x16x32_f16(a10, b1, oa0, 0, 0, 0);
            oa1 = __builtin_amdgcn_mfma_f32_16x16x32_f16(a11, b1, oa1, 0, 0, 0);
        }
        // C layout: col = nn (w within tile), row = q*4 + reg (j)
        const int n = p * 16 + nn;
#pragma unroll
        for (int reg = 0; reg < 4; reg++) {
            const int j  = q * 4 + reg;
            const int kk = j >> 1;
            const float v = oa0[reg] + off_b[g * 18 + j];
            if ((j & 1) == 0) pcs[kk][n].x = v + (float)(kk / 3) + (float)(h + 1);
            else              pcs[kk][n].y = v + (float)(kk % 3) + (float)(n + 1);
        }
        if (q == 0) {
            pcs[8][n].x = oa1[0] + off_b[g * 18 + 16] + 2.0f + (float)(h + 1);
            pcs[8][n].y = oa1[1] + off_b[g * 18 + 17] + 2.0f + (float)(n + 1);
        }
        // wave-private pcs: no barrier
    }

    // ---------------- Phase B: barrier-free gather + einsum pipeline ----------
    const int posL  = lane >> 3;      // 0..7: position within 8-group
    const int chidx = lane & 7;       // 8-channel chunk

    short* sW0 = &sT[p][0][0];
    short* sW1 = &sT[p][1][0];

    f32x4 acc[4] = { {0.f}, {0.f}, {0.f}, {0.f} };
    const short* dwg = dwA16 + g * KK * 4096;

    // issue the 8 corner loads of one tap into registers (no wait here)
    auto issue_tap = [&](int k, uint4* cr, float2* wv) {
#pragma unroll
        for (int it = 0; it < 2; it++) {
            const int pos = p * 16 + it * 8 + posL;
            const float2 pc = pcs[k][pos];
            const float yf = floorf(pc.x);
            const float xf = floorf(pc.y);
            wv[it] = make_float2(pc.x - yf, pc.y - xf);
            int y0 = (int)yf;
            int x0 = (int)xf;
            y0 = (y0 < 0) ? 0 : ((y0 > 66) ? 66 : y0);
            x0 = (x0 < 0) ? 0 : ((x0 > 66) ? 66 : x0);
            const short* cp = xb + (y0 * PD + x0) * CG + chidx * 8;
            cr[it * 4 + 0] = *(const uint4*)cp;
            cr[it * 4 + 1] = *(const uint4*)(cp + CG);
            cr[it * 4 + 2] = *(const uint4*)(cp + PD * CG);
            cr[it * 4 + 3] = *(const uint4*)(cp + PD * CG + CG);
        }
    };

    // consume the loaded corners: packed interp + wave-private LDS write
    auto write_tap = [&](short* __restrict__ sTb, const uint4* cr, const float2* wv) {
#pragma unroll
        for (int it = 0; it < 2; it++) {
            const float wy = wv[it].x;
            const float wx = wv[it].y;
            const float a00 = (1.0f - wy) * (1.0f - wx);
            const float a01 = (1.0f - wy) * wx;
            const float a10 = wy * (1.0f - wx);
            const float a11 = wy * wx;
            const h2 w00 = { (_Float16)a00, (_Float16)a00 };
            const h2 w01 = { (_Float16)a01, (_Float16)a01 };
            const h2 w10 = { (_Float16)a10, (_Float16)a10 };
            const h2 w11 = { (_Float16)a11, (_Float16)a11 };
            const uint4 c00 = cr[it * 4 + 0];
            const uint4 c01 = cr[it * 4 + 1];
            const uint4 c10 = cr[it * 4 + 2];
            const uint4 c11 = cr[it * 4 + 3];
            uint4 ov;
            ov.x = interp2h(c00.x, c01.x, c10.x, c11.x, w00, w01, w10, w11);
            ov.y = interp2h(c00.y, c01.y, c10.y, c11.y, w00, w01, w10, w11);
            ov.z = interp2h(c00.z, c01.z, c10.z, c11.z, w00, w01, w10, w11);
            ov.w = interp2h(c00.w, c01.w, c10.w, c11.w, w00, w01, w10, w11);
            *(uint4*)&sTb[(it * 8 + posL) * IP + chidx * 8] = ov;
        }
    };

    // einsum of one tap from the wave-private buffer (MFMA 16x16x32 f16)
    // B-frag: col = l&15 (pos), k = (l>>4)*8+e (+kh*32)
    auto einsum_tap = [&](int k, const short* __restrict__ sTb) {
        const short* dwk = dwg + k * 4096;
#pragma unroll
        for (int kh = 0; kh < 2; kh++) {
            const half8 bf = *(const half8*)&sTb[nn * IP + kh * 32 + q * 8];
#pragma unroll
            for (int ot = 0; ot < 4; ot++) {
                const half8 af = *(const half8*)(dwk + ((ot * 2 + kh) * 64 + lane) * 8);
                acc[ot] = __builtin_amdgcn_mfma_f32_16x16x32_f16(af, bf, acc[ot], 0, 0, 0);
            }
        }
    };

    uint4  crA[8], crB[8];
    float2 wvA[2], wvB[2];

    issue_tap(0, crA, wvA);
    write_tap(sW0, crA, wvA);
#pragma unroll
    for (int k = 0; k < KK; k++) {
        short*  bufCur = ((k & 1) == 0) ? sW0 : sW1;
        short*  bufNxt = ((k & 1) == 0) ? sW1 : sW0;
        uint4*  crN    = ((k & 1) == 0) ? crB : crA;
        float2* wvN    = ((k & 1) == 0) ? wvB : wvA;
        if (k < KK - 1) issue_tap(k + 1, crN, wvN);   // loads in flight across einsum
        einsum_tap(k, bufCur);
        if (k < KK - 1) write_tap(bufNxt, crN, wvN);
    }

    // ---------------- epilogue ----------------
    // C/D 16x16 layout: col = lane&15 (n), row = q*4 + reg (o within tile)
    float* outb = out + (size_t)(b * 256 + g * 64) * HW + h * W_;
    const int n = p * 16 + nn;
#pragma unroll
    for (int ot = 0; ot < 4; ot++) {
#pragma unroll
        for (int reg = 0; reg < 4; reg++) {
            const int o = ot * 16 + q * 4 + reg;
            outb[(size_t)o * HW + n] = acc[ot][reg] + def_b[g * 64 + o];
        }
    }
}

// ---------------------------------------------------------------------------
// Fallback (no workspace): round-1-style fused fp32 kernel, known correct.
// ---------------------------------------------------------------------------
__global__ __launch_bounds__(256, 4)
void deform_fallback(const float* __restrict__ x,
                     const float* __restrict__ off_w,
                     const float* __restrict__ off_b,
                     const float* __restrict__ def_w,
                     const float* __restrict__ def_b,
                     float* __restrict__ out)
{
    const int raw = blockIdx.x;
    const int r8  = raw & 7;
    const int h   = (raw >> 3) & 63;
    const int q8  = raw >> 9;
    const int bg  = q8 * 8 + r8;
    const int b   = bg >> 2;
    const int g   = bg & 3;

    __shared__ float pys[KK][W_];
    __shared__ float pxs[KK][W_];
    __shared__ float buf[8192];
    float* red   = buf;
    float* s_lds = buf;
    float* dwTl  = buf + 4096;

    const int t = threadIdx.x;
    const int w = t & 63;
    const int p = t >> 6;

    const float* xg = x + (size_t)(b * 256 + g * 64) * HW;

    float acc[18];
#pragma unroll
    for (int j = 0; j < 18; j++) acc[j] = 0.0f;
    {
        const int i0 = p * 16;
        for (int ii = 0; ii < 16; ii++) {
            const int i = i0 + ii;
            const float* xi = xg + i * HW;
#pragma unroll
            for (int r = 0; r < 3; r++) {
                const int y = h + r - 1;
                if ((unsigned)y >= (unsigned)H_) continue;
#pragma unroll
                for (int c = 0; c < 3; c++) {
                    const int xc = w + c - 1;
                    const float xv = ((unsigned)xc < (unsigned)W_) ? xi[y * W_ + xc] : 0.0f;
#pragma unroll
                    for (int j = 0; j < 18; j++) {
                        const float wv = off_w[((g * 18 + j) * CG + i) * 9 + r * 3 + c];
                        acc[j] = fmaf(wv, xv, acc[j]);
                    }
                }
            }
        }
    }
#pragma unroll
    for (int j = 0; j < 18; j++) red[(p * 18 + j) * 64 + w] = acc[j];
    __syncthreads();
    for (int idx = t; idx < 18 * 64; idx += 256) {
        const int j  = idx >> 6;
        const int ww = idx & 63;
        float v = red[(0 * 18 + j) * 64 + ww] + red[(1 * 18 + j) * 64 + ww]
                + red[(2 * 18 + j) * 64 + ww] + red[(3 * 18 + j) * 64 + ww];
        v += off_b[g * 18 + j];
        const int k = j >> 1;
        if ((j & 1) == 0) pys[k][ww] = v + (float)(k / 3 - 1) + (float)h;
        else              pxs[k][ww] = v + (float)(k % 3 - 1) + (float)ww;
    }
    __syncthreads();

    float facc[16];
#pragma unroll
    for (int qd = 0; qd < 16; qd++) facc[qd] = 0.0f;
    const int w4 = (t & 15) << 2;
    const int o4 = (t >> 4) << 2;

    for (int k = 0; k < KK; k++) {
#pragma unroll
        for (int n = 0; n < 16; n++) {
            const int v = t + 256 * n;
            const int i = v >> 6;
            const int o = v & 63;
            dwTl[v] = def_w[((g * CG + o) * CG + i) * KK + k];
        }
        const float py  = pys[k][w];
        const float px  = pxs[k][w];
        const float y0f = floorf(py);
        const float x0f = floorf(px);
        const float wy  = py - y0f;
        const float wx  = px - x0f;
        const int   y0  = (int)y0f;
        const int   x0  = (int)x0f;
        const float w00 = (1.0f - wy) * (1.0f - wx);
        const float w01 = (1.0f - wy) * wx;
        const float w10 = wy * (1.0f - wx);
        const float w11 = wy * wx;
        const bool vy0 = (unsigned)y0       < (unsigned)H_;
        const bool vy1 = (unsigned)(y0 + 1) < (unsigned)H_;
        const bool vx0 = (unsigned)x0       < (unsigned)W_;
        const bool vx1 = (unsigned)(x0 + 1) < (unsigned)W_;
        const int a00 = y0 * W_ + x0;
#pragma unroll
        for (int n = 0; n < 16; n++) {
            const int i = (n << 2) + p;
            const float* xi = xg + i * HW;
            const float v00 = (vy0 && vx0) ? xi[a00]          : 0.0f;
            const float v01 = (vy0 && vx1) ? xi[a00 + 1]      : 0.0f;
            const float v10 = (vy1 && vx0) ? xi[a00 + W_]     : 0.0f;
            const float v11 = (vy1 && vx1) ? xi[a00 + W_ + 1] : 0.0f;
            s_lds[i * 64 + w] = w00 * v00 + w01 * v01 + w10 * v10 + w11 * v11;
        }
        __syncthreads();
#pragma unroll 4
        for (int i = 0; i < CG; i++) {
            const float4 sv = *(const float4*)&s_lds[i * 64 + w4];
            const float4 dv = *(const float4*)&dwTl[i * 64 + o4];
            facc[0]  = fmaf(dv.x, sv.x, facc[0]);
            facc[1]  = fmaf(dv.x, sv.y, facc[1]);
            facc[2]  = fmaf(dv.x, sv.z, facc[2]);
            facc[3]  = fmaf(dv.x, sv.w, facc[3]);
            facc[4]  = fmaf(dv.y, sv.x, facc[4]);
            facc[5]  = fmaf(dv.y, sv.y, facc[5]);
            facc[6]  = fmaf(dv.y, sv.z, facc[6]);
            facc[7]  = fmaf(dv.y, sv.w, facc[7]);
            facc[8]  = fmaf(dv.z, sv.x, facc[8]);
            facc[9]  = fmaf(dv.z, sv.y, facc[9]);
            facc[10] = fmaf(dv.z, sv.z, facc[10]);
            facc[11] = fmaf(dv.z, sv.w, facc[11]);
            facc[12] = fmaf(dv.w, sv.x, facc[12]);
            facc[13] = fmaf(dv.w, sv.y, facc[13]);
            facc[14] = fmaf(dv.w, sv.z, facc[14]);
            facc[15] = fmaf(dv.w, sv.w, facc[15]);
        }
        __syncthreads();
    }

    float* outp = out + (size_t)(b * 256 + g * 64) * HW + h * W_;
#pragma unroll
    for (int oo = 0; oo < 4; oo++) {
        const int o = o4 + oo;
        const float bias = def_b[g * 64 + o];
        float4 r;
        r.x = facc[oo * 4 + 0] + bias;
        r.y = facc[oo * 4 + 1] + bias;
        r.z = facc[oo * 4 + 2] + bias;
        r.w = facc[oo * 4 + 3] + bias;
        *(float4*)&outp[o * HW + w4] = r;
    }
}

// ---------------------------------------------------------------------------
extern "C" void kernel_launch(void* const* d_in, const int* in_sizes, int n_in,
                              void* d_out, int out_size, void* d_ws, size_t ws_size,
                              hipStream_t stream)
{
    (void)in_sizes; (void)n_in; (void)out_size;
    const float* x     = (const float*)d_in[0];
    const float* off_w = (const float*)d_in[1];
    const float* off_b = (const float*)d_in[2];
    const float* def_w = (const float*)d_in[3];
    const float* def_b = (const float*)d_in[4];
    float* out = (float*)d_out;

    const size_t xT_bytes  = (size_t)B_ * G_ * XSLICE * 2;     // 37,879,808
    const size_t dw_bytes  = (size_t)G_ * KK * 4096 * 2;       // 294,912
    const size_t ow_bytes  = (size_t)G_ * 18 * 1024 * 2;       // 147,456
    const size_t need = xT_bytes + dw_bytes + ow_bytes;

    const int nblk   = B_ * G_ * H_;                     // 4096
    const int nprepw = (G_ * KK * 4096 + G_ * 18 * 1024 + 255) / 256;  // 864
    const int nprep  = 1024 + 64 + nprepw;               // x-tiles + zero rows + weights

    if (ws_size >= need) {
        short* xTpad = (short*)d_ws;
        short* dwA16 = (short*)((char*)d_ws + xT_bytes);
        short* owA   = (short*)((char*)d_ws + xT_bytes + dw_bytes);
        prep_all<<<nprep, 256, 0, stream>>>(x, off_w, def_w, xTpad, dwA16, owA);
        deform_main<<<nblk, 256, 0, stream>>>(xTpad, off_b, def_b, dwA16, owA, out);
    } else {
        deform_fallback<<<nblk, 256, 0, stream>>>(x, off_w, off_b, def_w, def_b, out);
    }
}

// Round 4
// 232.873 us; speedup vs baseline: 1.0072x; 1.0072x over previous
//
#include <hip/hip_runtime.h>
#include <hip/hip_bf16.h>
#include <hip/hip_fp16.h>

#define B_  16
#define G_  4
#define CG  64
#define H_  64
#define W_  64
#define KK  9
#define HW  (H_ * W_)
#define IP  72            // padded i-stride (shorts) for sT rows: 144 B
#define PD  68            // padded spatial dim (64 + 2 each side)
#define XSLICE (PD * PD * CG)   // shorts per (b,g) slice of xTpad

// staged window geometry: rows [h, h+4], cols 1..66, all 64 ch
#define WROWS 5
#define WCOLS 66
#define NCELL (WROWS * WCOLS)     // 330 cells of 128 B
#define NSLOT (NCELL * 8)         // 2640 16-B slots

typedef short    short8  __attribute__((ext_vector_type(8)));
typedef _Float16 half8   __attribute__((ext_vector_type(8)));
typedef _Float16 h2      __attribute__((ext_vector_type(2)));
typedef float    f32x4   __attribute__((ext_vector_type(4)));
typedef float    f32x16  __attribute__((ext_vector_type(16)));

__device__ __forceinline__ short f2h(float v) {
    _Float16 h = (_Float16)v;
    short s;
    __builtin_memcpy(&s, &h, 2);
    return s;
}

__device__ __forceinline__ unsigned int pk2h(float a, float b) {
    h2 h = { (_Float16)a, (_Float16)b };
    unsigned int u;
    __builtin_memcpy(&u, &h, 4);
    return u;
}

// bilinear combine of 2 packed fp16 channels via native v_pk_fma_f16
__device__ __forceinline__ unsigned int interp2h(unsigned int c00, unsigned int c01,
                                                 unsigned int c10, unsigned int c11,
                                                 h2 w00, h2 w01, h2 w10, h2 w11) {
    h2 v00, v01, v10, v11;
    __builtin_memcpy(&v00, &c00, 4);
    __builtin_memcpy(&v01, &c01, 4);
    __builtin_memcpy(&v10, &c10, 4);
    __builtin_memcpy(&v11, &c11, 4);
    h2 r = v00 * w00 + v01 * w01 + v10 * w10 + v11 * w11;
    unsigned int o;
    __builtin_memcpy(&o, &r, 4);
    return o;
}

// ---------------------------------------------------------------------------
// Merged prep kernel (fp16 staging).
//  blocks [0, 1024): interior x transpose. Block = (bg, 4-row y-tile).
//  blocks [1024, 1088): y-border zero rows (yp in {0,1,66,67}) per bg.
//  blocks [1088, +864): weight prep (r2 layouts: 32x32 einsum A-frags)
//   dwA32[g][k][mt][step][q2][o][e] f16 = def_w[g][mt*32+o][i=step*16+q2*8+e][k]
//   owA  [g][s][tm][q][jj][e]  f16 = off_w[g][j=tm*16+jj][(s&1)*32+q*8+e][s>>1]
// ---------------------------------------------------------------------------
__global__ __launch_bounds__(256)
void prep_all(const float* __restrict__ x,
              const float* __restrict__ off_w,
              const float* __restrict__ def_w,
              short* __restrict__ xTpad,
              short* __restrict__ dwA32,
              short* __restrict__ owA)
{
    const int blk = blockIdx.x;
    const int t   = threadIdx.x;

    if (blk < 1024) {
        const int bg = blk >> 4;
        const int y0 = (blk & 15) * 4;

        __shared__ unsigned int sBw[4 * CG * 33];   // 33792 B, f16x2 packed, padded

        const float* src = x + (size_t)bg * CG * HW + (size_t)y0 * W_;
        const int i  = t >> 2;          // channel 0..63
        const int x0 = (t & 3) * 16;    // col base 0/16/32/48

        // ---- load phase: 16 independent float4 loads per thread ----
        float4 v[4][4];
#pragma unroll
        for (int r = 0; r < 4; r++) {
            const float* sp = src + (size_t)i * HW + r * W_ + x0;
#pragma unroll
            for (int c = 0; c < 4; c++) v[r][c] = ((const float4*)sp)[c];
        }

        // ---- convert + stage (packed f16x2, padded row stride 33 words) ----
#pragma unroll
        for (int r = 0; r < 4; r++) {
#pragma unroll
            for (int c = 0; c < 4; c++) {
                const unsigned int u0 = pk2h(v[r][c].x, v[r][c].y);
                const unsigned int u1 = pk2h(v[r][c].z, v[r][c].w);
                const int base = (r * CG + i) * 33 + ((x0 + 4 * c) >> 1);
                sBw[base]     = u0;
                sBw[base + 1] = u1;
            }
        }
        __syncthreads();

        // ---- transpose-out phase: 16B stores, column reads hit 8 banks ----
        const short* sBs = (const short*)sBw;
        short* dst = xTpad + (size_t)bg * XSLICE;
#pragma unroll
        for (int r = 0; r < 4; r++) {
            const int yp = y0 + 2 + r;
            for (int task = t; task < PD * 8; task += 256) {
                const int ich = task & 7;
                const int xp  = task >> 3;
                const int xx  = xp - 2;
                short8 o = {0, 0, 0, 0, 0, 0, 0, 0};
                if ((unsigned)xx < (unsigned)W_) {
#pragma unroll
                    for (int e = 0; e < 8; e++)
                        o[e] = sBs[(r * CG + ich * 8 + e) * 66 + xx];
                }
                *(short8*)(dst + ((size_t)yp * PD + xp) * CG + ich * 8) = o;
            }
        }
        return;
    }

    if (blk < 1088) {
        // y-border zero rows: yp in {0,1} and {66,67}
        const int bg = blk - 1024;
        short* dstb = xTpad + (size_t)bg * XSLICE;
        const int4 z = {0, 0, 0, 0};
        int4* d0 = (int4*)(dstb);
        int4* d1 = (int4*)(dstb + (size_t)66 * PD * CG);
        const int n16 = (2 * PD * CG * 2) / 16;   // 1088 int4 per 2-row band
        for (int c = t; c < n16; c += 256) { d0[c] = z; d1[c] = z; }
        return;
    }

    // ---- weights part (r2 layouts) ----
    const int tid = (blk - 1088) * 256 + t;
    const int ndw = G_ * KK * 4096;               // 147456
    const int now = G_ * 18 * 2 * 4 * 16 * 8;     // 73728
    if (tid < ndw) {
        const int e    = tid & 7;
        const int o    = (tid >> 3) & 31;
        const int q2   = (tid >> 8) & 1;
        const int step = (tid >> 9) & 3;
        const int mt   = (tid >> 11) & 1;
        const int gk   = tid >> 12;
        const int k    = gk % KK;
        const int g    = gk / KK;
        const int oo   = mt * 32 + o;
        const int i    = step * 16 + q2 * 8 + e;
        dwA32[tid] = f2h(def_w[((g * CG + oo) * CG + i) * KK + k]);
    } else if (tid < ndw + now) {
        const int t2 = tid - ndw;
        const int e  = t2 & 7;
        const int jj = (t2 >> 3) & 15;
        const int q  = (t2 >> 7) & 3;
        const int tm = (t2 >> 9) & 1;
        const int gs = t2 >> 10;
        const int s  = gs % 18;
        const int g  = gs / 18;
        const int j  = tm * 16 + jj;
        const int rc = s >> 1;
        const int i  = (s & 1) * 32 + q * 8 + e;
        owA[t2] = (j < 18) ? f2h(off_w[((g * 18 + j) * CG + i) * KK + rc]) : (short)0;
    }
}

// ---------------------------------------------------------------------------
// Main fused kernel (fp16, LDS-staged x window). Block = (b,g,h), 256 thr.
//  Stage rows [h,h+4] x cols 1..66 x 64ch of xTpad into LDS (42.2 KB,
//  per-cell chunk XOR swizzle -> bank-uniform reads for ANY offset pattern).
//  Phase A reads its conv window from LDS; Phase B bilinear-gathers from LDS
//  (rare out-of-window samples fall back to global). Einsum = r2's shared-sT
//  MFMA 32x32x16 with 1 barrier/tap.
// ---------------------------------------------------------------------------
__global__ __launch_bounds__(256, 2)
void deform_main(const short* __restrict__ xTpad,
                 const float* __restrict__ off_b,
                 const float* __restrict__ def_b,
                 const short* __restrict__ dwA32,
                 const short* __restrict__ owA,
                 float* __restrict__ out)
{
    const int raw = blockIdx.x;
    const int r8  = raw & 7;
    const int h   = (raw >> 3) & 63;
    const int q8  = raw >> 9;
    const int bg  = q8 * 8 + r8;
    const int b   = bg >> 2;
    const int g   = bg & 3;

    __shared__ short  sX[NSLOT * 8];        // 42,240 B staged x window (swizzled)
    __shared__ float2 pcs[KK][64];          // 4,608 B
    __shared__ short  sT[2][64 * IP];       // 18,432 B       (total 65,280 B)

    const int t    = threadIdx.x;
    const int lane = t & 63;
    const int p    = t >> 6;          // wave id 0..3
    const int nn   = lane & 15;
    const int q    = lane >> 4;

    const short* xb = xTpad + (size_t)bg * XSLICE;

    // ---------------- stage x window: global -> regs -> swizzled LDS ----------
    {
        uint4 tmp[10];
#pragma unroll
        for (int j = 0; j < 10; j++) {
            const int s    = j * 256 + t;
            const int cell = s >> 3;
            const int c    = (s & 7) ^ (cell & 7);
            const int rr   = cell / WCOLS;
            const int colx = 1 + (cell - rr * WCOLS);
            tmp[j] = *(const uint4*)(xb + ((h + rr) * PD + colx) * CG + c * 8);
        }
        uint4 tl;
        const int st = 2560 + t;
        if (t < NSLOT - 2560) {
            const int cell = st >> 3;
            const int c    = (st & 7) ^ (cell & 7);
            const int rr   = cell / WCOLS;
            const int colx = 1 + (cell - rr * WCOLS);
            tl = *(const uint4*)(xb + ((h + rr) * PD + colx) * CG + c * 8);
        }
#pragma unroll
        for (int j = 0; j < 10; j++) *(uint4*)&sX[(j * 256 + t) * 8] = tmp[j];
        if (t < NSLOT - 2560) *(uint4*)&sX[st * 8] = tl;
    }
    __syncthreads();

    // ---------------- Phase A: offset conv (MFMA 16x16x32 f16, B from LDS) ----
    {
        const short* owAg = owA + g * 18 * 1024;
        f32x4 oa0 = {0.f, 0.f, 0.f, 0.f};
        f32x4 oa1 = {0.f, 0.f, 0.f, 0.f};
#pragma unroll
        for (int rc = 0; rc < 9; rc++) {
            const int rr = rc / 3;
            const int cc = rc % 3;
            const int cA   = p * 16 + nn + cc + 1;            // 1..66
            const int cell = (rr + 1) * WCOLS + (cA - 1);
            const half8 b0 = *(const half8*)&sX[(cell * 8 + ( q      ^ (cell & 7))) * 8];
            const half8 b1 = *(const half8*)&sX[(cell * 8 + ((q + 4) ^ (cell & 7))) * 8];
            const int s0 = rc * 2, s1 = rc * 2 + 1;
            const half8 a00 = *(const half8*)(owAg + ((s0 * 2 + 0) * 4 + q) * 128 + nn * 8);
            const half8 a01 = *(const half8*)(owAg + ((s0 * 2 + 1) * 4 + q) * 128 + nn * 8);
            const half8 a10 = *(const half8*)(owAg + ((s1 * 2 + 0) * 4 + q) * 128 + nn * 8);
            const half8 a11 = *(const half8*)(owAg + ((s1 * 2 + 1) * 4 + q) * 128 + nn * 8);
            oa0 = __builtin_amdgcn_mfma_f32_16x16x32_f16(a00, b0, oa0, 0, 0, 0);
            oa1 = __builtin_amdgcn_mfma_f32_16x16x32_f16(a01, b0, oa1, 0, 0, 0);
            oa0 = __builtin_amdgcn_mfma_f32_16x16x32_f16(a10, b1, oa0, 0, 0, 0);
            oa1 = __builtin_amdgcn_mfma_f32_16x16x32_f16(a11, b1, oa1, 0, 0, 0);
        }
        // C layout: col = nn (w within tile), row = q*4 + reg (j)
        const int n = p * 16 + nn;
#pragma unroll
        for (int reg = 0; reg < 4; reg++) {
            const int j  = q * 4 + reg;
            const int kk = j >> 1;
            const float v = oa0[reg] + off_b[g * 18 + j];
            if ((j & 1) == 0) pcs[kk][n].x = v + (float)(kk / 3) + (float)(h + 1);
            else              pcs[kk][n].y = v + (float)(kk % 3) + (float)(n + 1);
        }
        if (q == 0) {
            pcs[8][n].x = oa1[0] + off_b[g * 18 + 16] + 2.0f + (float)(h + 1);
            pcs[8][n].y = oa1[1] + off_b[g * 18 + 17] + 2.0f + (float)(n + 1);
        }
        // each wave reads only its own tile's coords in the gather: no barrier
    }

    // ---------------- Phase B: gather (LDS) + einsum, double-buffered ---------
    const int mt  = p >> 1;           // einsum output 32-row tile
    const int nt  = p & 1;            // einsum output 32-col tile
    const int n31 = lane & 31;
    const int q2  = lane >> 5;

    f32x16 acc = {0.f};
    const short* dwg = dwA32 + g * KK * 4096;

    const int posL  = lane >> 3;      // 0..7: position within 8-group
    const int chidx = lane & 7;       // 8-channel chunk

    // gather of one tap into buffer sTb: 8 lanes/pos, 8 ch/lane, 16B LDS loads
    auto gather_tap = [&](int k, short* __restrict__ sTb) {
#pragma unroll
        for (int it = 0; it < 2; it++) {
            const int pos = p * 16 + it * 8 + posL;
            const float2 pc = pcs[k][pos];
            const float yf = floorf(pc.x);
            const float xf = floorf(pc.y);
            const float wy = pc.x - yf;
            const float wx = pc.y - xf;
            int y0 = (int)yf;
            int x0 = (int)xf;
            y0 = (y0 < 0) ? 0 : ((y0 > 66) ? 66 : y0);
            x0 = (x0 < 0) ? 0 : ((x0 > 66) ? 66 : x0);
            float a00 = (1.0f - wy) * (1.0f - wx);
            float a01 = (1.0f - wy) * wx;
            float a10 = wy * (1.0f - wx);
            float a11 = wy * wx;
            uint4 c00, c01, c10, c11;
            const int ry = y0 - h;
            if (ry >= 0 && ry <= WROWS - 2) {
                // LDS path: cols 0 and 67 are all-zero -> zero their weights
                int col0 = x0 - 1;
                int col1 = x0;
                if (col0 < 0)          { a00 = 0.f; a10 = 0.f; col0 = 0; }
                if (col1 > WCOLS - 1)  { a01 = 0.f; a11 = 0.f; col1 = WCOLS - 1; }
                const int ca = ry * WCOLS + col0;
                const int cb = ry * WCOLS + col1;
                const int cc_ = ca + WCOLS;
                const int cd = cb + WCOLS;
                c00 = *(const uint4*)&sX[(ca  * 8 + (chidx ^ (ca  & 7))) * 8];
                c01 = *(const uint4*)&sX[(cb  * 8 + (chidx ^ (cb  & 7))) * 8];
                c10 = *(const uint4*)&sX[(cc_ * 8 + (chidx ^ (cc_ & 7))) * 8];
                c11 = *(const uint4*)&sX[(cd  * 8 + (chidx ^ (cd  & 7))) * 8];
            } else {
                // rare out-of-window sample: global path (exact r2 semantics)
                const short* cp = xb + (y0 * PD + x0) * CG + chidx * 8;
                c00 = *(const uint4*)cp;
                c01 = *(const uint4*)(cp + CG);
                c10 = *(const uint4*)(cp + PD * CG);
                c11 = *(const uint4*)(cp + PD * CG + CG);
            }
            const h2 w00 = { (_Float16)a00, (_Float16)a00 };
            const h2 w01 = { (_Float16)a01, (_Float16)a01 };
            const h2 w10 = { (_Float16)a10, (_Float16)a10 };
            const h2 w11 = { (_Float16)a11, (_Float16)a11 };
            uint4 ov;
            ov.x = interp2h(c00.x, c01.x, c10.x, c11.x, w00, w01, w10, w11);
            ov.y = interp2h(c00.y, c01.y, c10.y, c11.y, w00, w01, w10, w11);
            ov.z = interp2h(c00.z, c01.z, c10.z, c11.z, w00, w01, w10, w11);
            ov.w = interp2h(c00.w, c01.w, c10.w, c11.w, w00, w01, w10, w11);
            *(uint4*)&sTb[pos * IP + chidx * 8] = ov;
        }
    };

    // einsum of one tap from buffer sTb (MFMA 32x32x16 f16)
    auto einsum_tap = [&](int k, const short* __restrict__ sTb) {
        const short* dwk = dwg + k * 4096;
#pragma unroll
        for (int step = 0; step < 4; step++) {
            const half8 af = *(const half8*)(dwk + ((mt * 4 + step) * 2 + q2) * 256 + n31 * 8);
            const half8 bf = *(const half8*)&sTb[(nt * 32 + n31) * IP + step * 16 + q2 * 8];
            acc = __builtin_amdgcn_mfma_f32_32x32x16_f16(af, bf, acc, 0, 0, 0);
        }
    };

    gather_tap(0, &sT[0][0]);
    __syncthreads();
    for (int k = 0; k < KK; k++) {
        if (k < KK - 1) gather_tap(k + 1, &sT[(k + 1) & 1][0]);
        einsum_tap(k, &sT[k & 1][0]);
        __syncthreads();
    }

    // ---------------- epilogue ----------------
    // C/D 32x32 layout: col = lane&31, row = (reg&3) + 8*(reg>>2) + 4*q2
    float* outb = out + (size_t)(b * 256 + g * 64) * HW + h * W_;
    const int n = nt * 32 + n31;
#pragma unroll
    for (int reg = 0; reg < 16; reg++) {
        const int o = mt * 32 + (reg & 3) + 8 * (reg >> 2) + 4 * q2;
        outb[(size_t)o * HW + n] = acc[reg] + def_b[g * 64 + o];
    }
}

// ---------------------------------------------------------------------------
// Fallback (no workspace): round-1-style fused fp32 kernel, known correct.
// ---------------------------------------------------------------------------
__global__ __launch_bounds__(256, 4)
void deform_fallback(const float* __restrict__ x,
                     const float* __restrict__ off_w,
                     const float* __restrict__ off_b,
                     const float* __restrict__ def_w,
                     const float* __restrict__ def_b,
                     float* __restrict__ out)
{
    const int raw = blockIdx.x;
    const int r8  = raw & 7;
    const int h   = (raw >> 3) & 63;
    const int q8  = raw >> 9;
    const int bg  = q8 * 8 + r8;
    const int b   = bg >> 2;
    const int g   = bg & 3;

    __shared__ float pys[KK][W_];
    __shared__ float pxs[KK][W_];
    __shared__ float buf[8192];
    float* red   = buf;
    float* s_lds = buf;
    float* dwTl  = buf + 4096;

    const int t = threadIdx.x;
    const int w = t & 63;
    const int p = t >> 6;

    const float* xg = x + (size_t)(b * 256 + g * 64) * HW;

    float acc[18];
#pragma unroll
    for (int j = 0; j < 18; j++) acc[j] = 0.0f;
    {
        const int i0 = p * 16;
        for (int ii = 0; ii < 16; ii++) {
            const int i = i0 + ii;
            const float* xi = xg + i * HW;
#pragma unroll
            for (int r = 0; r < 3; r++) {
                const int y = h + r - 1;
                if ((unsigned)y >= (unsigned)H_) continue;
#pragma unroll
                for (int c = 0; c < 3; c++) {
                    const int xc = w + c - 1;
                    const float xv = ((unsigned)xc < (unsigned)W_) ? xi[y * W_ + xc] : 0.0f;
#pragma unroll
                    for (int j = 0; j < 18; j++) {
                        const float wv = off_w[((g * 18 + j) * CG + i) * 9 + r * 3 + c];
                        acc[j] = fmaf(wv, xv, acc[j]);
                    }
                }
            }
        }
    }
#pragma unroll
    for (int j = 0; j < 18; j++) red[(p * 18 + j) * 64 + w] = acc[j];
    __syncthreads();
    for (int idx = t; idx < 18 * 64; idx += 256) {
        const int j  = idx >> 6;
        const int ww = idx & 63;
        float v = red[(0 * 18 + j) * 64 + ww] + red[(1 * 18 + j) * 64 + ww]
                + red[(2 * 18 + j) * 64 + ww] + red[(3 * 18 + j) * 64 + ww];
        v += off_b[g * 18 + j];
        const int k = j >> 1;
        if ((j & 1) == 0) pys[k][ww] = v + (float)(k / 3 - 1) + (float)h;
        else              pxs[k][ww] = v + (float)(k % 3 - 1) + (float)ww;
    }
    __syncthreads();

    float facc[16];
#pragma unroll
    for (int qd = 0; qd < 16; qd++) facc[qd] = 0.0f;
    const int w4 = (t & 15) << 2;
    const int o4 = (t >> 4) << 2;

    for (int k = 0; k < KK; k++) {
#pragma unroll
        for (int n = 0; n < 16; n++) {
            const int v = t + 256 * n;
            const int i = v >> 6;
            const int o = v & 63;
            dwTl[v] = def_w[((g * CG + o) * CG + i) * KK + k];
        }
        const float py  = pys[k][w];
        const float px  = pxs[k][w];
        const float y0f = floorf(py);
        const float x0f = floorf(px);
        const float wy  = py - y0f;
        const float wx  = px - x0f;
        const int   y0  = (int)y0f;
        const int   x0  = (int)x0f;
        const float w00 = (1.0f - wy) * (1.0f - wx);
        const float w01 = (1.0f - wy) * wx;
        const float w10 = wy * (1.0f - wx);
        const float w11 = wy * wx;
        const bool vy0 = (unsigned)y0       < (unsigned)H_;
        const bool vy1 = (unsigned)(y0 + 1) < (unsigned)H_;
        const bool vx0 = (unsigned)x0       < (unsigned)W_;
        const bool vx1 = (unsigned)(x0 + 1) < (unsigned)W_;
        const int a00 = y0 * W_ + x0;
#pragma unroll
        for (int n = 0; n < 16; n++) {
            const int i = (n << 2) + p;
            const float* xi = xg + i * HW;
            const float v00 = (vy0 && vx0) ? xi[a00]          : 0.0f;
            const float v01 = (vy0 && vx1) ? xi[a00 + 1]      : 0.0f;
            const float v10 = (vy1 && vx0) ? xi[a00 + W_]     : 0.0f;
            const float v11 = (vy1 && vx1) ? xi[a00 + W_ + 1] : 0.0f;
            s_lds[i * 64 + w] = w00 * v00 + w01 * v01 + w10 * v10 + w11 * v11;
        }
        __syncthreads();
#pragma unroll 4
        for (int i = 0; i < CG; i++) {
            const float4 sv = *(const float4*)&s_lds[i * 64 + w4];
            const float4 dv = *(const float4*)&dwTl[i * 64 + o4];
            facc[0]  = fmaf(dv.x, sv.x, facc[0]);
            facc[1]  = fmaf(dv.x, sv.y, facc[1]);
            facc[2]  = fmaf(dv.x, sv.z, facc[2]);
            facc[3]  = fmaf(dv.x, sv.w, facc[3]);
            facc[4]  = fmaf(dv.y, sv.x, facc[4]);
            facc[5]  = fmaf(dv.y, sv.y, facc[5]);
            facc[6]  = fmaf(dv.y, sv.z, facc[6]);
            facc[7]  = fmaf(dv.y, sv.w, facc[7]);
            facc[8]  = fmaf(dv.z, sv.x, facc[8]);
            facc[9]  = fmaf(dv.z, sv.y, facc[9]);
            facc[10] = fmaf(dv.z, sv.z, facc[10]);
            facc[11] = fmaf(dv.z, sv.w, facc[11]);
            facc[12] = fmaf(dv.w, sv.x, facc[12]);
            facc[13] = fmaf(dv.w, sv.y, facc[13]);
            facc[14] = fmaf(dv.w, sv.z, facc[14]);
            facc[15] = fmaf(dv.w, sv.w, facc[15]);
        }
        __syncthreads();
    }

    float* outp = out + (size_t)(b * 256 + g * 64) * HW + h * W_;
#pragma unroll
    for (int oo = 0; oo < 4; oo++) {
        const int o = o4 + oo;
        const float bias = def_b[g * 64 + o];
        float4 r;
        r.x = facc[oo * 4 + 0] + bias;
        r.y = facc[oo * 4 + 1] + bias;
        r.z = facc[oo * 4 + 2] + bias;
        r.w = facc[oo * 4 + 3] + bias;
        *(float4*)&outp[o * HW + w4] = r;
    }
}

// ---------------------------------------------------------------------------
extern "C" void kernel_launch(void* const* d_in, const int* in_sizes, int n_in,
                              void* d_out, int out_size, void* d_ws, size_t ws_size,
                              hipStream_t stream)
{
    (void)in_sizes; (void)n_in; (void)out_size;
    const float* x     = (const float*)d_in[0];
    const float* off_w = (const float*)d_in[1];
    const float* off_b = (const float*)d_in[2];
    const float* def_w = (const float*)d_in[3];
    const float* def_b = (const float*)d_in[4];
    float* out = (float*)d_out;

    const size_t xT_bytes  = (size_t)B_ * G_ * XSLICE * 2;     // 37,879,808
    const size_t dw_bytes  = (size_t)G_ * KK * 4096 * 2;       // 294,912
    const size_t ow_bytes  = (size_t)G_ * 18 * 1024 * 2;       // 147,456
    const size_t need = xT_bytes + dw_bytes + ow_bytes;

    const int nblk   = B_ * G_ * H_;                     // 4096
    const int nprepw = (G_ * KK * 4096 + G_ * 18 * 1024 + 255) / 256;  // 864
    const int nprep  = 1024 + 64 + nprepw;               // x-tiles + zero rows + weights

    if (ws_size >= need) {
        short* xTpad = (short*)d_ws;
        short* dwA32 = (short*)((char*)d_ws + xT_bytes);
        short* owA   = (short*)((char*)d_ws + xT_bytes + dw_bytes);
        prep_all<<<nprep, 256, 0, stream>>>(x, off_w, def_w, xTpad, dwA32, owA);
        deform_main<<<nblk, 256, 0, stream>>>(xTpad, off_b, def_b, dwA32, owA, out);
    } else {
        deform_fallback<<<nblk, 256, 0, stream>>>(x, off_w, off_b, def_w, def_b, out);
    }
}

// Round 5
// 219.151 us; speedup vs baseline: 1.0703x; 1.0626x over previous
//
#include <hip/hip_runtime.h>
#include <hip/hip_bf16.h>
#include <hip/hip_fp16.h>

#define B_  16
#define G_  4
#define CG  64
#define H_  64
#define W_  64
#define KK  9
#define HW  (H_ * W_)
#define IP  72            // padded i-stride (shorts) for sT rows: 144 B
#define PD  68            // padded spatial dim (64 + 2 each side)
#define XSLICE (PD * PD * CG)   // shorts per (b,g) slice of xTpad

typedef short    short8  __attribute__((ext_vector_type(8)));
typedef _Float16 half8   __attribute__((ext_vector_type(8)));
typedef _Float16 h2      __attribute__((ext_vector_type(2)));
typedef float    f32x4   __attribute__((ext_vector_type(4)));
typedef float    f32x16  __attribute__((ext_vector_type(16)));

__device__ __forceinline__ short f2h(float v) {
    _Float16 h = (_Float16)v;
    short s;
    __builtin_memcpy(&s, &h, 2);
    return s;
}

__device__ __forceinline__ unsigned int pk2h(float a, float b) {
    h2 h = { (_Float16)a, (_Float16)b };
    unsigned int u;
    __builtin_memcpy(&u, &h, 4);
    return u;
}

// bilinear combine of 2 packed fp16 channels via native v_pk_fma_f16
__device__ __forceinline__ unsigned int interp2h(unsigned int c00, unsigned int c01,
                                                 unsigned int c10, unsigned int c11,
                                                 h2 w00, h2 w01, h2 w10, h2 w11) {
    h2 v00, v01, v10, v11;
    __builtin_memcpy(&v00, &c00, 4);
    __builtin_memcpy(&v01, &c01, 4);
    __builtin_memcpy(&v10, &c10, 4);
    __builtin_memcpy(&v11, &c11, 4);
    h2 r = v00 * w00 + v01 * w01 + v10 * w10 + v11 * w11;
    unsigned int o;
    __builtin_memcpy(&o, &r, 4);
    return o;
}

// ---------------------------------------------------------------------------
// Merged prep kernel (fp16 staging).
//  blocks [0, 1024): interior x transpose. Block = (bg, 4-row y-tile).
//  blocks [1024, 1088): y-border zero rows (yp in {0,1,66,67}) per bg.
//  blocks [1088, +864): weight prep
//   dwA32[g][k][mt][step][q2][o][e] f16 = def_w[g][mt*32+o][i=step*16+q2*8+e][k]
//   owA  [g][s][tm][q][jj][e]  f16 = off_w[g][j=tm*16+jj][(s&1)*32+q*8+e][s>>1]
// ---------------------------------------------------------------------------
__global__ __launch_bounds__(256)
void prep_all(const float* __restrict__ x,
              const float* __restrict__ off_w,
              const float* __restrict__ def_w,
              short* __restrict__ xTpad,
              short* __restrict__ dwA32,
              short* __restrict__ owA)
{
    const int blk = blockIdx.x;
    const int t   = threadIdx.x;

    if (blk < 1024) {
        const int bg = blk >> 4;
        const int y0 = (blk & 15) * 4;

        __shared__ unsigned int sBw[4 * CG * 33];   // 33792 B, f16x2 packed, padded

        const float* src = x + (size_t)bg * CG * HW + (size_t)y0 * W_;
        const int i  = t >> 2;          // channel 0..63
        const int x0 = (t & 3) * 16;    // col base 0/16/32/48

        // ---- load phase: 16 independent float4 loads per thread ----
        float4 v[4][4];
#pragma unroll
        for (int r = 0; r < 4; r++) {
            const float* sp = src + (size_t)i * HW + r * W_ + x0;
#pragma unroll
            for (int c = 0; c < 4; c++) v[r][c] = ((const float4*)sp)[c];
        }

        // ---- convert + stage (packed f16x2, padded row stride 33 words) ----
#pragma unroll
        for (int r = 0; r < 4; r++) {
#pragma unroll
            for (int c = 0; c < 4; c++) {
                const unsigned int u0 = pk2h(v[r][c].x, v[r][c].y);
                const unsigned int u1 = pk2h(v[r][c].z, v[r][c].w);
                const int base = (r * CG + i) * 33 + ((x0 + 4 * c) >> 1);
                sBw[base]     = u0;
                sBw[base + 1] = u1;
            }
        }
        __syncthreads();

        // ---- transpose-out phase: 16B stores, column reads hit 8 banks ----
        const short* sBs = (const short*)sBw;
        short* dst = xTpad + (size_t)bg * XSLICE;
#pragma unroll
        for (int r = 0; r < 4; r++) {
            const int yp = y0 + 2 + r;
            for (int task = t; task < PD * 8; task += 256) {
                const int ich = task & 7;
                const int xp  = task >> 3;
                const int xx  = xp - 2;
                short8 o = {0, 0, 0, 0, 0, 0, 0, 0};
                if ((unsigned)xx < (unsigned)W_) {
#pragma unroll
                    for (int e = 0; e < 8; e++)
                        o[e] = sBs[(r * CG + ich * 8 + e) * 66 + xx];
                }
                *(short8*)(dst + ((size_t)yp * PD + xp) * CG + ich * 8) = o;
            }
        }
        return;
    }

    if (blk < 1088) {
        // y-border zero rows: yp in {0,1} and {66,67}
        const int bg = blk - 1024;
        short* dstb = xTpad + (size_t)bg * XSLICE;
        const int4 z = {0, 0, 0, 0};
        int4* d0 = (int4*)(dstb);
        int4* d1 = (int4*)(dstb + (size_t)66 * PD * CG);
        const int n16 = (2 * PD * CG * 2) / 16;   // 1088 int4 per 2-row band
        for (int c = t; c < n16; c += 256) { d0[c] = z; d1[c] = z; }
        return;
    }

    // ---- weights part ----
    const int tid = (blk - 1088) * 256 + t;
    const int ndw = G_ * KK * 4096;               // 147456
    const int now = G_ * 18 * 2 * 4 * 16 * 8;     // 73728
    if (tid < ndw) {
        const int e    = tid & 7;
        const int o    = (tid >> 3) & 31;
        const int q2   = (tid >> 8) & 1;
        const int step = (tid >> 9) & 3;
        const int mt   = (tid >> 11) & 1;
        const int gk   = tid >> 12;
        const int k    = gk % KK;
        const int g    = gk / KK;
        const int oo   = mt * 32 + o;
        const int i    = step * 16 + q2 * 8 + e;
        dwA32[tid] = f2h(def_w[((g * CG + oo) * CG + i) * KK + k]);
    } else if (tid < ndw + now) {
        const int t2 = tid - ndw;
        const int e  = t2 & 7;
        const int jj = (t2 >> 3) & 15;
        const int q  = (t2 >> 7) & 3;
        const int tm = (t2 >> 9) & 1;
        const int gs = t2 >> 10;
        const int s  = gs % 18;
        const int g  = gs / 18;
        const int j  = tm * 16 + jj;
        const int rc = s >> 1;
        const int i  = (s & 1) * 32 + q * 8 + e;
        owA[t2] = (j < 18) ? f2h(off_w[((g * 18 + j) * CG + i) * KK + rc]) : (short)0;
    }
}

// ---------------------------------------------------------------------------
// Main fused kernel (fp16). Block = (b, g, h), 256 threads, 4 waves.
//  r2 structure (shared sT, MFMA 32x32x16 einsum, 1 barrier/tap) + T14 split:
//  issue gather loads of tap k+1 (named uint4 regs, no arrays -> no scratch)
//  -> einsum tap k (af loads + MFMAs cover the gather latency)
//  -> interp + sT write of tap k+1 (first use of loaded regs = waitcnt here).
// ---------------------------------------------------------------------------
__global__ __launch_bounds__(256, 4)
void deform_main(const short* __restrict__ xTpad,
                 const float* __restrict__ off_b,
                 const float* __restrict__ def_b,
                 const short* __restrict__ dwA32,
                 const short* __restrict__ owA,
                 float* __restrict__ out)
{
    const int raw = blockIdx.x;
    const int r8  = raw & 7;
    const int h   = (raw >> 3) & 63;
    const int q8  = raw >> 9;
    const int bg  = q8 * 8 + r8;
    const int b   = bg >> 2;
    const int g   = bg & 3;

    __shared__ float2 pcs[KK][64];          // .x = padded py, .y = padded px
    __shared__ short  sT[2][64 * IP];

    const int t    = threadIdx.x;
    const int lane = t & 63;
    const int p    = t >> 6;          // wave id 0..3
    const int nn   = lane & 15;
    const int q    = lane >> 4;

    const short* xb = xTpad + (size_t)bg * XSLICE;

    // ---------------- Phase A: offset conv (MFMA 16x16x32 f16) ----------------
    {
        const short* owAg = owA + g * 18 * 1024;
        f32x4 oa0 = {0.f, 0.f, 0.f, 0.f};
        f32x4 oa1 = {0.f, 0.f, 0.f, 0.f};
#pragma unroll
        for (int rc = 0; rc < 9; rc++) {
            const int rr = rc / 3;
            const int cc = rc % 3;
            const short* cp = xb + ((h + rr + 1) * PD + (p * 16 + nn + cc + 1)) * CG + q * 8;
            const half8 b0 = *(const half8*)cp;          // s = 2rc   (ih=0)
            const half8 b1 = *(const half8*)(cp + 32);   // s = 2rc+1 (ih=32)
            const int s0 = rc * 2, s1 = rc * 2 + 1;
            const half8 a00 = *(const half8*)(owAg + ((s0 * 2 + 0) * 4 + q) * 128 + nn * 8);
            const half8 a01 = *(const half8*)(owAg + ((s0 * 2 + 1) * 4 + q) * 128 + nn * 8);
            const half8 a10 = *(const half8*)(owAg + ((s1 * 2 + 0) * 4 + q) * 128 + nn * 8);
            const half8 a11 = *(const half8*)(owAg + ((s1 * 2 + 1) * 4 + q) * 128 + nn * 8);
            oa0 = __builtin_amdgcn_mfma_f32_16x16x32_f16(a00, b0, oa0, 0, 0, 0);
            oa1 = __builtin_amdgcn_mfma_f32_16x16x32_f16(a01, b0, oa1, 0, 0, 0);
            oa0 = __builtin_amdgcn_mfma_f32_16x16x32_f16(a10, b1, oa0, 0, 0, 0);
            oa1 = __builtin_amdgcn_mfma_f32_16x16x32_f16(a11, b1, oa1, 0, 0, 0);
        }
        // C layout: col = nn (w within tile), row = q*4 + reg (j)
        const int n = p * 16 + nn;
#pragma unroll
        for (int reg = 0; reg < 4; reg++) {
            const int j  = q * 4 + reg;
            const int kk = j >> 1;
            const float v = oa0[reg] + off_b[g * 18 + j];
            if ((j & 1) == 0) pcs[kk][n].x = v + (float)(kk / 3) + (float)(h + 1);
            else              pcs[kk][n].y = v + (float)(kk % 3) + (float)(n + 1);
        }
        if (q == 0) {
            pcs[8][n].x = oa1[0] + off_b[g * 18 + 16] + 2.0f + (float)(h + 1);
            pcs[8][n].y = oa1[1] + off_b[g * 18 + 17] + 2.0f + (float)(n + 1);
        }
        // each wave reads only its own tile's coords in the gather: no barrier
    }

    // ---------------- Phase B: gather + einsum, T14-split pipeline ------------
    const int mt  = p >> 1;           // einsum output 32-row tile
    const int nt  = p & 1;            // einsum output 32-col tile
    const int n31 = lane & 31;
    const int q2  = lane >> 5;

    f32x16 acc = {0.f};
    const short* dwg = dwA32 + g * KK * 4096;

    const int posL  = lane >> 3;      // 0..7: position within 8-group
    const int chidx = lane & 7;       // 8-channel chunk
    const int posA  = p * 16 + posL;      // this lane's first position
    const int posB  = posA + 8;           // this lane's second position

    // in-flight gather state: NAMED variables only (rule #20: no arrays)
    uint4 ca00, ca01, ca10, ca11;
    uint4 cb00, cb01, cb10, cb11;
    float wya, wxa, wyb, wxb;

    // issue the 8 corner loads of one tap into named registers (no use -> no wait)
    auto issue_g = [&](int k) {
        {
            const float2 pc = pcs[k][posA];
            const float yf = floorf(pc.x);
            const float xf = floorf(pc.y);
            wya = pc.x - yf;
            wxa = pc.y - xf;
            int y0 = (int)yf;
            int x0 = (int)xf;
            y0 = (y0 < 0) ? 0 : ((y0 > 66) ? 66 : y0);
            x0 = (x0 < 0) ? 0 : ((x0 > 66) ? 66 : x0);
            const short* cp = xb + (y0 * PD + x0) * CG + chidx * 8;
            ca00 = *(const uint4*)cp;
            ca01 = *(const uint4*)(cp + CG);
            ca10 = *(const uint4*)(cp + PD * CG);
            ca11 = *(const uint4*)(cp + PD * CG + CG);
        }
        {
            const float2 pc = pcs[k][posB];
            const float yf = floorf(pc.x);
            const float xf = floorf(pc.y);
            wyb = pc.x - yf;
            wxb = pc.y - xf;
            int y0 = (int)yf;
            int x0 = (int)xf;
            y0 = (y0 < 0) ? 0 : ((y0 > 66) ? 66 : y0);
            x0 = (x0 < 0) ? 0 : ((x0 > 66) ? 66 : x0);
            const short* cp = xb + (y0 * PD + x0) * CG + chidx * 8;
            cb00 = *(const uint4*)cp;
            cb01 = *(const uint4*)(cp + CG);
            cb10 = *(const uint4*)(cp + PD * CG);
            cb11 = *(const uint4*)(cp + PD * CG + CG);
        }
    };

    // consume the in-flight corners: packed interp + shared-sT write
    auto write_t = [&](short* __restrict__ sTb) {
        {
            const float a00 = (1.0f - wya) * (1.0f - wxa);
            const float a01 = (1.0f - wya) * wxa;
            const float a10 = wya * (1.0f - wxa);
            const float a11 = wya * wxa;
            const h2 w00 = { (_Float16)a00, (_Float16)a00 };
            const h2 w01 = { (_Float16)a01, (_Float16)a01 };
            const h2 w10 = { (_Float16)a10, (_Float16)a10 };
            const h2 w11 = { (_Float16)a11, (_Float16)a11 };
            uint4 ov;
            ov.x = interp2h(ca00.x, ca01.x, ca10.x, ca11.x, w00, w01, w10, w11);
            ov.y = interp2h(ca00.y, ca01.y, ca10.y, ca11.y, w00, w01, w10, w11);
            ov.z = interp2h(ca00.z, ca01.z, ca10.z, ca11.z, w00, w01, w10, w11);
            ov.w = interp2h(ca00.w, ca01.w, ca10.w, ca11.w, w00, w01, w10, w11);
            *(uint4*)&sTb[posA * IP + chidx * 8] = ov;
        }
        {
            const float a00 = (1.0f - wyb) * (1.0f - wxb);
            const float a01 = (1.0f - wyb) * wxb;
            const float a10 = wyb * (1.0f - wxb);
            const float a11 = wyb * wxb;
            const h2 w00 = { (_Float16)a00, (_Float16)a00 };
            const h2 w01 = { (_Float16)a01, (_Float16)a01 };
            const h2 w10 = { (_Float16)a10, (_Float16)a10 };
            const h2 w11 = { (_Float16)a11, (_Float16)a11 };
            uint4 ov;
            ov.x = interp2h(cb00.x, cb01.x, cb10.x, cb11.x, w00, w01, w10, w11);
            ov.y = interp2h(cb00.y, cb01.y, cb10.y, cb11.y, w00, w01, w10, w11);
            ov.z = interp2h(cb00.z, cb01.z, cb10.z, cb11.z, w00, w01, w10, w11);
            ov.w = interp2h(cb00.w, cb01.w, cb10.w, cb11.w, w00, w01, w10, w11);
            *(uint4*)&sTb[posB * IP + chidx * 8] = ov;
        }
    };

    // einsum of one tap from buffer sTb (MFMA 32x32x16 f16); af loads hoisted
    auto einsum_t = [&](int k, const short* __restrict__ sTb) {
        const short* dwk = dwg + k * 4096;
        const half8 af0 = *(const half8*)(dwk + ((mt * 4 + 0) * 2 + q2) * 256 + n31 * 8);
        const half8 af1 = *(const half8*)(dwk + ((mt * 4 + 1) * 2 + q2) * 256 + n31 * 8);
        const half8 af2 = *(const half8*)(dwk + ((mt * 4 + 2) * 2 + q2) * 256 + n31 * 8);
        const half8 af3 = *(const half8*)(dwk + ((mt * 4 + 3) * 2 + q2) * 256 + n31 * 8);
        const half8 bf0 = *(const half8*)&sTb[(nt * 32 + n31) * IP + 0 * 16 + q2 * 8];
        const half8 bf1 = *(const half8*)&sTb[(nt * 32 + n31) * IP + 1 * 16 + q2 * 8];
        const half8 bf2 = *(const half8*)&sTb[(nt * 32 + n31) * IP + 2 * 16 + q2 * 8];
        const half8 bf3 = *(const half8*)&sTb[(nt * 32 + n31) * IP + 3 * 16 + q2 * 8];
        acc = __builtin_amdgcn_mfma_f32_32x32x16_f16(af0, bf0, acc, 0, 0, 0);
        acc = __builtin_amdgcn_mfma_f32_32x32x16_f16(af1, bf1, acc, 0, 0, 0);
        acc = __builtin_amdgcn_mfma_f32_32x32x16_f16(af2, bf2, acc, 0, 0, 0);
        acc = __builtin_amdgcn_mfma_f32_32x32x16_f16(af3, bf3, acc, 0, 0, 0);
    };

    issue_g(0);
    write_t(&sT[0][0]);
    __syncthreads();
#pragma unroll
    for (int k = 0; k < KK; k++) {
        if (k < KK - 1) issue_g(k + 1);          // 8 loads in flight...
        einsum_t(k, &sT[k & 1][0]);              // ...covered by af/bf + MFMAs
        if (k < KK - 1) write_t(&sT[(k + 1) & 1][0]);  // first use -> waitcnt here
        __syncthreads();
    }

    // ---------------- epilogue ----------------
    // C/D 32x32 layout: col = lane&31, row = (reg&3) + 8*(reg>>2) + 4*q2
    float* outb = out + (size_t)(b * 256 + g * 64) * HW + h * W_;
    const int n = nt * 32 + n31;
#pragma unroll
    for (int reg = 0; reg < 16; reg++) {
        const int o = mt * 32 + (reg & 3) + 8 * (reg >> 2) + 4 * q2;
        outb[(size_t)o * HW + n] = acc[reg] + def_b[g * 64 + o];
    }
}

// ---------------------------------------------------------------------------
// Fallback (no workspace): round-1-style fused fp32 kernel, known correct.
// ---------------------------------------------------------------------------
__global__ __launch_bounds__(256, 4)
void deform_fallback(const float* __restrict__ x,
                     const float* __restrict__ off_w,
                     const float* __restrict__ off_b,
                     const float* __restrict__ def_w,
                     const float* __restrict__ def_b,
                     float* __restrict__ out)
{
    const int raw = blockIdx.x;
    const int r8  = raw & 7;
    const int h   = (raw >> 3) & 63;
    const int q8  = raw >> 9;
    const int bg  = q8 * 8 + r8;
    const int b   = bg >> 2;
    const int g   = bg & 3;

    __shared__ float pys[KK][W_];
    __shared__ float pxs[KK][W_];
    __shared__ float buf[8192];
    float* red   = buf;
    float* s_lds = buf;
    float* dwTl  = buf + 4096;

    const int t = threadIdx.x;
    const int w = t & 63;
    const int p = t >> 6;

    const float* xg = x + (size_t)(b * 256 + g * 64) * HW;

    float acc[18];
#pragma unroll
    for (int j = 0; j < 18; j++) acc[j] = 0.0f;
    {
        const int i0 = p * 16;
        for (int ii = 0; ii < 16; ii++) {
            const int i = i0 + ii;
            const float* xi = xg + i * HW;
#pragma unroll
            for (int r = 0; r < 3; r++) {
                const int y = h + r - 1;
                if ((unsigned)y >= (unsigned)H_) continue;
#pragma unroll
                for (int c = 0; c < 3; c++) {
                    const int xc = w + c - 1;
                    const float xv = ((unsigned)xc < (unsigned)W_) ? xi[y * W_ + xc] : 0.0f;
#pragma unroll
                    for (int j = 0; j < 18; j++) {
                        const float wv = off_w[((g * 18 + j) * CG + i) * 9 + r * 3 + c];
                        acc[j] = fmaf(wv, xv, acc[j]);
                    }
                }
            }
        }
    }
#pragma unroll
    for (int j = 0; j < 18; j++) red[(p * 18 + j) * 64 + w] = acc[j];
    __syncthreads();
    for (int idx = t; idx < 18 * 64; idx += 256) {
        const int j  = idx >> 6;
        const int ww = idx & 63;
        float v = red[(0 * 18 + j) * 64 + ww] + red[(1 * 18 + j) * 64 + ww]
                + red[(2 * 18 + j) * 64 + ww] + red[(3 * 18 + j) * 64 + ww];
        v += off_b[g * 18 + j];
        const int k = j >> 1;
        if ((j & 1) == 0) pys[k][ww] = v + (float)(k / 3 - 1) + (float)h;
        else              pxs[k][ww] = v + (float)(k % 3 - 1) + (float)ww;
    }
    __syncthreads();

    float facc[16];
#pragma unroll
    for (int qd = 0; qd < 16; qd++) facc[qd] = 0.0f;
    const int w4 = (t & 15) << 2;
    const int o4 = (t >> 4) << 2;

    for (int k = 0; k < KK; k++) {
#pragma unroll
        for (int n = 0; n < 16; n++) {
            const int v = t + 256 * n;
            const int i = v >> 6;
            const int o = v & 63;
            dwTl[v] = def_w[((g * CG + o) * CG + i) * KK + k];
        }
        const float py  = pys[k][w];
        const float px  = pxs[k][w];
        const float y0f = floorf(py);
        const float x0f = floorf(px);
        const float wy  = py - y0f;
        const float wx  = px - x0f;
        const int   y0  = (int)y0f;
        const int   x0  = (int)x0f;
        const float w00 = (1.0f - wy) * (1.0f - wx);
        const float w01 = (1.0f - wy) * wx;
        const float w10 = wy * (1.0f - wx);
        const float w11 = wy * wx;
        const bool vy0 = (unsigned)y0       < (unsigned)H_;
        const bool vy1 = (unsigned)(y0 + 1) < (unsigned)H_;
        const bool vx0 = (unsigned)x0       < (unsigned)W_;
        const bool vx1 = (unsigned)(x0 + 1) < (unsigned)W_;
        const int a00 = y0 * W_ + x0;
#pragma unroll
        for (int n = 0; n < 16; n++) {
            const int i = (n << 2) + p;
            const float* xi = xg + i * HW;
            const float v00 = (vy0 && vx0) ? xi[a00]          : 0.0f;
            const float v01 = (vy0 && vx1) ? xi[a00 + 1]      : 0.0f;
            const float v10 = (vy1 && vx0) ? xi[a00 + W_]     : 0.0f;
            const float v11 = (vy1 && vx1) ? xi[a00 + W_ + 1] : 0.0f;
            s_lds[i * 64 + w] = w00 * v00 + w01 * v01 + w10 * v10 + w11 * v11;
        }
        __syncthreads();
#pragma unroll 4
        for (int i = 0; i < CG; i++) {
            const float4 sv = *(const float4*)&s_lds[i * 64 + w4];
            const float4 dv = *(const float4*)&dwTl[i * 64 + o4];
            facc[0]  = fmaf(dv.x, sv.x, facc[0]);
            facc[1]  = fmaf(dv.x, sv.y, facc[1]);
            facc[2]  = fmaf(dv.x, sv.z, facc[2]);
            facc[3]  = fmaf(dv.x, sv.w, facc[3]);
            facc[4]  = fmaf(dv.y, sv.x, facc[4]);
            facc[5]  = fmaf(dv.y, sv.y, facc[5]);
            facc[6]  = fmaf(dv.y, sv.z, facc[6]);
            facc[7]  = fmaf(dv.y, sv.w, facc[7]);
            facc[8]  = fmaf(dv.z, sv.x, facc[8]);
            facc[9]  = fmaf(dv.z, sv.y, facc[9]);
            facc[10] = fmaf(dv.z, sv.z, facc[10]);
            facc[11] = fmaf(dv.z, sv.w, facc[11]);
            facc[12] = fmaf(dv.w, sv.x, facc[12]);
            facc[13] = fmaf(dv.w, sv.y, facc[13]);
            facc[14] = fmaf(dv.w, sv.z, facc[14]);
            facc[15] = fmaf(dv.w, sv.w, facc[15]);
        }
        __syncthreads();
    }

    float* outp = out + (size_t)(b * 256 + g * 64) * HW + h * W_;
#pragma unroll
    for (int oo = 0; oo < 4; oo++) {
        const int o = o4 + oo;
        const float bias = def_b[g * 64 + o];
        float4 r;
        r.x = facc[oo * 4 + 0] + bias;
        r.y = facc[oo * 4 + 1] + bias;
        r.z = facc[oo * 4 + 2] + bias;
        r.w = facc[oo * 4 + 3] + bias;
        *(float4*)&outp[o * HW + w4] = r;
    }
}

// ---------------------------------------------------------------------------
extern "C" void kernel_launch(void* const* d_in, const int* in_sizes, int n_in,
                              void* d_out, int out_size, void* d_ws, size_t ws_size,
                              hipStream_t stream)
{
    (void)in_sizes; (void)n_in; (void)out_size;
    const float* x     = (const float*)d_in[0];
    const float* off_w = (const float*)d_in[1];
    const float* off_b = (const float*)d_in[2];
    const float* def_w = (const float*)d_in[3];
    const float* def_b = (const float*)d_in[4];
    float* out = (float*)d_out;

    const size_t xT_bytes  = (size_t)B_ * G_ * XSLICE * 2;     // 37,879,808
    const size_t dw_bytes  = (size_t)G_ * KK * 4096 * 2;       // 294,912
    const size_t ow_bytes  = (size_t)G_ * 18 * 1024 * 2;       // 147,456
    const size_t need = xT_bytes + dw_bytes + ow_bytes;

    const int nblk   = B_ * G_ * H_;                     // 4096
    const int nprepw = (G_ * KK * 4096 + G_ * 18 * 1024 + 255) / 256;  // 864
    const int nprep  = 1024 + 64 + nprepw;               // x-tiles + zero rows + weights

    if (ws_size >= need) {
        short* xTpad = (short*)d_ws;
        short* dwA32 = (short*)((char*)d_ws + xT_bytes);
        short* owA   = (short*)((char*)d_ws + xT_bytes + dw_bytes);
        prep_all<<<nprep, 256, 0, stream>>>(x, off_w, def_w, xTpad, dwA32, owA);
        deform_main<<<nblk, 256, 0, stream>>>(xTpad, off_b, def_b, dwA32, owA, out);
    } else {
        deform_fallback<<<nblk, 256, 0, stream>>>(x, off_w, off_b, def_w, def_b, out);
    }
}